// Round 1
// 926.478 us; speedup vs baseline: 1.2939x; 1.2939x over previous
//
#include <hip/hip_runtime.h>
#include <cstdint>
#include <cstddef>

#define IN_DIM 768
#define OUT_DIM 128
#define N_NODES 100000
#define N_EDGES 1600000

typedef __bf16 bf16x8 __attribute__((ext_vector_type(8)));
typedef float f32x4 __attribute__((ext_vector_type(4)));

static __device__ __forceinline__ unsigned short f2bf(float f) {
  unsigned u = __builtin_bit_cast(unsigned, f);
  u += 0x7fffu + ((u >> 16) & 1u);      // round-to-nearest-even
  return (unsigned short)(u >> 16);
}
static __device__ __forceinline__ float bflo(unsigned u) {
  return __builtin_bit_cast(float, u << 16);
}
static __device__ __forceinline__ float bfhi(unsigned u) {
  return __builtin_bit_cast(float, u & 0xffff0000u);
}

// ---------------- CSR build ----------------

__global__ void deg_kernel(const int* __restrict__ src, const int* __restrict__ dst,
                           int* __restrict__ out_deg, int* __restrict__ in_deg) {
  int e = blockIdx.x * 256 + threadIdx.x;
  if (e < N_EDGES) {
    atomicAdd(&out_deg[src[e]], 1);
    atomicAdd(&in_deg[dst[e]], 1);
  }
}

__global__ void norm_kernel(const int* __restrict__ out_deg, float* __restrict__ norm_src) {
  int i = blockIdx.x * 256 + threadIdx.x;
  if (i < N_NODES) norm_src[i] = rsqrtf(fmaxf((float)out_deg[i], 1.0f));
}

// ---- 3-phase multi-block exclusive scan of in_deg -> row_start[0..N_NODES] ----
// Phase A: per-block (1024 elems) exclusive scan + block total
__global__ __launch_bounds__(256) void scanA_kernel(const int* __restrict__ in_deg,
                                                    int* __restrict__ row_start,
                                                    int* __restrict__ blk_sums) {
  __shared__ int sm[256];
  const int tid = threadIdx.x;
  const int base = blockIdx.x * 1024;
  int idx = base + tid * 4;
  int v0 = (idx + 0 < N_NODES) ? in_deg[idx + 0] : 0;
  int v1 = (idx + 1 < N_NODES) ? in_deg[idx + 1] : 0;
  int v2 = (idx + 2 < N_NODES) ? in_deg[idx + 2] : 0;
  int v3 = (idx + 3 < N_NODES) ? in_deg[idx + 3] : 0;
  int t0 = v0, t1 = t0 + v1, t2 = t1 + v2, t3 = t2 + v3;
  sm[tid] = t3;
  __syncthreads();
  for (int off = 1; off < 256; off <<= 1) {
    int x = (tid >= off) ? sm[tid - off] : 0;
    __syncthreads();
    sm[tid] += x;
    __syncthreads();
  }
  int base_sum = tid ? sm[tid - 1] : 0;
  if (idx + 0 < N_NODES) row_start[idx + 0] = base_sum;
  if (idx + 1 < N_NODES) row_start[idx + 1] = base_sum + t0;
  if (idx + 2 < N_NODES) row_start[idx + 2] = base_sum + t1;
  if (idx + 3 < N_NODES) row_start[idx + 3] = base_sum + t2;
  if (tid == 255) blk_sums[blockIdx.x] = sm[255];
}

// Phase B: scan of the 98 block totals (one block, 128 threads)
__global__ void scanB_kernel(const int* __restrict__ blk_sums, int* __restrict__ blk_off) {
  __shared__ int sm[128];
  const int tid = threadIdx.x;
  const int nblk = (N_NODES + 1023) / 1024;
  int v = (tid < nblk) ? blk_sums[tid] : 0;
  sm[tid] = v;
  __syncthreads();
  for (int off = 1; off < 128; off <<= 1) {
    int x = (tid >= off) ? sm[tid - off] : 0;
    __syncthreads();
    sm[tid] += x;
    __syncthreads();
  }
  blk_off[tid] = tid ? sm[tid - 1] : 0;
}

// Phase C: add block offsets; also write cursor copy + sentinel
__global__ void scanC_kernel(int* __restrict__ row_start, const int* __restrict__ blk_off,
                             int* __restrict__ cursor) {
  int i = blockIdx.x * 256 + threadIdx.x;
  if (i < N_NODES) {
    int v = row_start[i] + blk_off[i >> 10];
    row_start[i] = v;
    cursor[i] = v;
  }
  if (i == 0) row_start[N_NODES] = N_EDGES;
}

__global__ void scatter_kernel(const int* __restrict__ src, const int* __restrict__ dst,
                               int* __restrict__ cursor, int* __restrict__ edge_src) {
  int e = blockIdx.x * 256 + threadIdx.x;
  if (e < N_EDGES) {
    int p = atomicAdd(&cursor[dst[e]], 1);
    edge_src[p] = src[e];
  }
}

// ---------------- Wd pre-transpose to bf16: WdT[n][k] ----------------

__global__ void wdt_kernel(const float* __restrict__ Wd, unsigned short* __restrict__ WdT) {
  int n = blockIdx.x;          // 0..127
  int k = threadIdx.x;         // 0..767
  WdT[(size_t)n * IN_DIM + k] = f2bf(Wd[(size_t)k * OUT_DIM + n]);
}

// ---------------- GEMM1: h_bf16 = bf16((feat @ Wd + bd) * norm_src) ----------------
// BM=64, BN=128 (full), BK=64, 4 waves each 32x64, mfma 16x16x32 bf16

__global__ __launch_bounds__(256) void gemm1_kernel(
    const float* __restrict__ feat, const unsigned short* __restrict__ WdT,
    const float* __restrict__ bd, const float* __restrict__ norm_src,
    unsigned short* __restrict__ hbf) {
  __shared__ unsigned short a_lds[64][72];    // [m][k], pad 64->72
  __shared__ unsigned short b_lds[128][72];   // [n][k]
  const int tid = threadIdx.x;
  const int wave = tid >> 6;
  const int lane = tid & 63;
  const int mrow = (wave >> 1) * 32;
  const int ncol = (wave & 1) * 64;
  const int block_m = blockIdx.x * 64;
  const int fm = lane & 15;
  const int fq = lane >> 4;

  f32x4 acc[2][4] = {};

  for (int k0 = 0; k0 < IN_DIM; k0 += 64) {
    // stage A: 64 rows x 64 k fp32 -> bf16  (1024 float4 chunks)
#pragma unroll
    for (int p = 0; p < 4; ++p) {
      int idx = tid + p * 256;
      int r = idx >> 4;
      int c4 = (idx & 15) * 4;
      int gr = block_m + r;
      float4 v;
      if (gr < N_NODES) v = *(const float4*)(feat + (size_t)gr * IN_DIM + k0 + c4);
      else v = make_float4(0.f, 0.f, 0.f, 0.f);
      ushort4 s;
      s.x = f2bf(v.x); s.y = f2bf(v.y); s.z = f2bf(v.z); s.w = f2bf(v.w);
      *(ushort4*)&a_lds[r][c4] = s;
    }
    // stage B: 128 n-rows x 64 k bf16 from WdT  (1024 uint4 chunks)
#pragma unroll
    for (int p = 0; p < 4; ++p) {
      int idx = tid + p * 256;
      int n = idx >> 3;
      int ch = (idx & 7) * 8;
      uint4 v = *(const uint4*)(WdT + (size_t)n * IN_DIM + k0 + ch);
      *(uint4*)&b_lds[n][ch] = v;
    }
    __syncthreads();
#pragma unroll
    for (int ks = 0; ks < 64; ks += 32) {
      int kc = ks + fq * 8;
      bf16x8 af[2], bfr[4];
      af[0] = *(const bf16x8*)&a_lds[mrow + fm][kc];
      af[1] = *(const bf16x8*)&a_lds[mrow + 16 + fm][kc];
#pragma unroll
      for (int i = 0; i < 4; ++i)
        bfr[i] = *(const bf16x8*)&b_lds[ncol + i * 16 + fm][kc];
#pragma unroll
      for (int mi = 0; mi < 2; ++mi)
#pragma unroll
        for (int ni = 0; ni < 4; ++ni)
          acc[mi][ni] = __builtin_amdgcn_mfma_f32_16x16x32_bf16(af[mi], bfr[ni], acc[mi][ni], 0, 0, 0);
    }
    __syncthreads();
  }
  // epilogue: (acc + bd[col]) * norm_src[row] -> bf16
  const int fr = fq * 4;
#pragma unroll
  for (int mi = 0; mi < 2; ++mi) {
#pragma unroll
    for (int r = 0; r < 4; ++r) {
      int row = block_m + mrow + mi * 16 + fr + r;
      if (row < N_NODES) {
        float ns = norm_src[row];
#pragma unroll
        for (int ni = 0; ni < 4; ++ni) {
          int col = ncol + ni * 16 + fm;
          float val = (acc[mi][ni][r] + bd[col]) * ns;
          hbf[(size_t)row * OUT_DIM + col] = f2bf(val);
        }
      }
    }
  }
}

// ---------------- aggregation: one wave per dst node ----------------

__global__ __launch_bounds__(256) void agg_kernel(
    const unsigned short* __restrict__ hbf, const int* __restrict__ row_start,
    const int* __restrict__ edge_src, unsigned short* __restrict__ aggb) {
  const int wave = threadIdx.x >> 6;
  const int lane = threadIdx.x & 63;
  const int v = blockIdx.x * 4 + wave;
  if (v >= N_NODES) return;
  const int beg = row_start[v];
  const int end = row_start[v + 1];
  const unsigned* hp = (const unsigned*)hbf;  // 64 uints per node row (128 bf16)
  float a0 = 0.f, a1 = 0.f;
  for (int c = beg; c < end; c += 64) {
    int rem = end - c;
    int n = rem < 64 ? rem : 64;
    int sv = (c + lane < end) ? edge_src[c + lane] : 0;
    int j = 0;
    for (; j + 4 <= n; j += 4) {
      int s0 = __shfl(sv, j + 0);
      int s1 = __shfl(sv, j + 1);
      int s2 = __shfl(sv, j + 2);
      int s3 = __shfl(sv, j + 3);
      unsigned u0 = hp[(size_t)s0 * 64 + lane];
      unsigned u1 = hp[(size_t)s1 * 64 + lane];
      unsigned u2 = hp[(size_t)s2 * 64 + lane];
      unsigned u3 = hp[(size_t)s3 * 64 + lane];
      a0 += (bflo(u0) + bflo(u1)) + (bflo(u2) + bflo(u3));
      a1 += (bfhi(u0) + bfhi(u1)) + (bfhi(u2) + bfhi(u3));
    }
    for (; j < n; ++j) {
      int s = __shfl(sv, j);
      unsigned u = hp[(size_t)s * 64 + lane];
      a0 += bflo(u);
      a1 += bfhi(u);
    }
  }
  float nd = rsqrtf(fmaxf((float)(end - beg), 1.0f));
  a0 *= nd; a1 *= nd;
  unsigned o = (unsigned)f2bf(a0) | ((unsigned)f2bf(a1) << 16);
  ((unsigned*)aggb)[(size_t)v * 64 + lane] = o;
}

// ---------------- fold Wg@Wu and bg@Wu+bu ----------------

__global__ void wgu_kernel(const float* __restrict__ Wg, const float* __restrict__ Wu,
                           unsigned short* __restrict__ WguT) {
  int i = blockIdx.x * 256 + threadIdx.x;     // over 128*768
  if (i >= 128 * 768) return;
  int r = i / 768, c = i % 768;
  float s = 0.f;
  for (int k = 0; k < 128; ++k) s += Wg[r * 128 + k] * Wu[(size_t)k * 768 + c];
  WguT[(size_t)c * 128 + r] = f2bf(s);        // stored transposed: [n=768][k=128]
}

__global__ void bgu_kernel(const float* __restrict__ bg, const float* __restrict__ Wu,
                           const float* __restrict__ bu, float* __restrict__ bgu) {
  int c = blockIdx.x * 256 + threadIdx.x;
  if (c >= 768) return;
  float s = bu[c];
  for (int k = 0; k < 128; ++k) s += bg[k] * Wu[(size_t)k * 768 + c];
  bgu[c] = s;
}

// ---------------- GEMM3: out = agg_bf16 @ Wgu + bgu (fp32 out) ----------------
// BM=128, BN=128, K=128 (two 64-wide stages), 4 waves each 64x64

__global__ __launch_bounds__(256) void gemm3_kernel(
    const unsigned short* __restrict__ aggb, const unsigned short* __restrict__ WguT,
    const float* __restrict__ bgu, float* __restrict__ out) {
  __shared__ unsigned short a_lds[128][72];   // [m][k], pad 64->72
  __shared__ unsigned short b_lds[128][72];   // [n][k]
  const int tid = threadIdx.x;
  const int wave = tid >> 6;
  const int lane = tid & 63;
  const int m_off = (wave >> 1) * 64;
  const int n_off = (wave & 1) * 64;
  const int block_m = blockIdx.x * 128;
  const int block_n = blockIdx.y * 128;
  const int fm = lane & 15;
  const int fq = lane >> 4;

  f32x4 acc[4][4] = {};

  for (int k0 = 0; k0 < 128; k0 += 64) {
    // stage A tile 128 rows x 64 bf16 = 128 x 8 uint4 chunks = 1024 chunks
#pragma unroll
    for (int p = 0; p < 4; ++p) {
      int idx = tid + p * 256;        // [0,1024)
      int r = idx >> 3, ch = idx & 7;
      int gr = block_m + r;
      uint4 v;
      if (gr < N_NODES) v = *(const uint4*)(aggb + (size_t)gr * 128 + k0 + ch * 8);
      else v = make_uint4(0u, 0u, 0u, 0u);
      *(uint4*)&a_lds[r][ch * 8] = v;
    }
    // stage B tile 128 n-rows x 64 bf16
#pragma unroll
    for (int p = 0; p < 4; ++p) {
      int idx = tid + p * 256;        // [0,1024)
      int n = idx >> 3, ch = idx & 7;
      uint4 v = *(const uint4*)(WguT + (size_t)(block_n + n) * 128 + k0 + ch * 8);
      *(uint4*)&b_lds[n][ch * 8] = v;
    }
    __syncthreads();
#pragma unroll
    for (int ks = 0; ks < 64; ks += 32) {
      bf16x8 af[4], bfr[4];
      int kc = ks + fq * 8;
#pragma unroll
      for (int i = 0; i < 4; ++i) af[i] = *(const bf16x8*)&a_lds[m_off + i * 16 + fm][kc];
#pragma unroll
      for (int i = 0; i < 4; ++i) bfr[i] = *(const bf16x8*)&b_lds[n_off + i * 16 + fm][kc];
#pragma unroll
      for (int mi = 0; mi < 4; ++mi)
#pragma unroll
        for (int ni = 0; ni < 4; ++ni)
          acc[mi][ni] = __builtin_amdgcn_mfma_f32_16x16x32_bf16(af[mi], bfr[ni], acc[mi][ni], 0, 0, 0);
    }
    __syncthreads();
  }
  const int fr = fq * 4;
#pragma unroll
  for (int mi = 0; mi < 4; ++mi) {
#pragma unroll
    for (int r = 0; r < 4; ++r) {
      int row = block_m + m_off + mi * 16 + fr + r;
      if (row < N_NODES) {
#pragma unroll
        for (int ni = 0; ni < 4; ++ni) {
          int col = block_n + n_off + ni * 16 + fm;
          out[(size_t)row * IN_DIM + col] = acc[mi][ni][r] + bgu[col];
        }
      }
    }
  }
}

// ---------------- launch ----------------

extern "C" void kernel_launch(void* const* d_in, const int* in_sizes, int n_in,
                              void* d_out, int out_size, void* d_ws, size_t ws_size,
                              hipStream_t stream) {
  (void)in_sizes; (void)n_in; (void)out_size; (void)ws_size;
  const float* feat = (const float*)d_in[0];
  const float* Wd   = (const float*)d_in[1];
  const float* bd   = (const float*)d_in[2];
  const float* Wg   = (const float*)d_in[3];
  const float* bg   = (const float*)d_in[4];
  const float* Wu   = (const float*)d_in[5];
  const float* bu   = (const float*)d_in[6];
  const int*   src  = (const int*)d_in[7];
  const int*   dst  = (const int*)d_in[8];
  float* out = (float*)d_out;

  char* ws = (char*)d_ws;
  unsigned short* hbf       = (unsigned short*)(ws + 0);          // 25,600,000
  unsigned short* aggb      = (unsigned short*)(ws + 25600000);   // 25,600,000
  int*            edge_srcs = (int*)(ws + 51200000);              //  6,400,000
  int*            out_deg   = (int*)(ws + 57600000);              //    400,000
  int*            in_deg    = (int*)(ws + 58000000);              //    400,000
  int*            row_start = (int*)(ws + 58400000);              //    400,004
  int*            cursor    = (int*)(ws + 58800128);              //    400,000
  float*          norm_src  = (float*)(ws + 59200128);            //    400,000
  unsigned short* WguT      = (unsigned short*)(ws + 59600128);   //    196,608
  float*          bgu       = (float*)(ws + 59796736);            //      3,072
  unsigned short* WdT       = (unsigned short*)(ws + 59799808);   //    196,608
  int*            blk_sums  = (int*)(ws + 59996416);              //        512
  int*            blk_off   = (int*)(ws + 59996928);              //        512

  // zero both degree arrays (contiguous 800,000 B)
  hipMemsetAsync(out_deg, 0, 800000, stream);
  deg_kernel<<<(N_EDGES + 255) / 256, 256, 0, stream>>>(src, dst, out_deg, in_deg);
  norm_kernel<<<(N_NODES + 255) / 256, 256, 0, stream>>>(out_deg, norm_src);
  scanA_kernel<<<(N_NODES + 1023) / 1024, 256, 0, stream>>>(in_deg, row_start, blk_sums);
  scanB_kernel<<<1, 128, 0, stream>>>(blk_sums, blk_off);
  scanC_kernel<<<(N_NODES + 255) / 256, 256, 0, stream>>>(row_start, blk_off, cursor);
  scatter_kernel<<<(N_EDGES + 255) / 256, 256, 0, stream>>>(src, dst, cursor, edge_srcs);
  wdt_kernel<<<128, 768, 0, stream>>>(Wd, WdT);
  gemm1_kernel<<<(N_NODES + 63) / 64, 256, 0, stream>>>(feat, WdT, bd, norm_src, hbf);
  agg_kernel<<<(N_NODES + 3) / 4, 256, 0, stream>>>(hbf, row_start, edge_srcs, aggb);
  wgu_kernel<<<(128 * 768 + 255) / 256, 256, 0, stream>>>(Wg, Wu, WguT);
  bgu_kernel<<<3, 256, 0, stream>>>(bg, Wu, bu, bgu);
  gemm3_kernel<<<dim3((N_NODES + 127) / 128, 6), 256, 0, stream>>>(aggb, WguT, bgu, out);
}